// Round 7
// baseline (209.349 us; speedup 1.0000x reference)
//
#include <hip/hip_runtime.h>

// Problem constants (fixed by setup_inputs)
#define B   8
#define C   256
#define H   128
#define W   128
#define HW  (H * W)
#define FH  512
#define FW  512

// Tiling
#define TR   16            // output rows per tile
#define SR   (TR + 7)      // staged rows [ybase-3, ybase+TR+3] = 23
#define CG   8             // channels per block
#define RG   (H / TR)      // 8 row-groups
#define CGN  (C / CG)      // 32 channel-groups
#define PXT  (TR * W / 256) // 8 pixels per thread
#define CHUNKS (SR * W / 4) // 736 float4 chunks per staged channel

// ---------------------------------------------------------------------------
// Kernel 1: strided 4x4 conv downsample of flows using runtime conv_w.
// ---------------------------------------------------------------------------
__global__ __launch_bounds__(256) void downsample_kernel(
    const float* __restrict__ flows,
    const float* __restrict__ conv_w,
    float* __restrict__ f)
{
    int idx = blockIdx.x * blockDim.x + threadIdx.x;
    if (idx >= B * 2 * H * W) return;
    int x = idx & (W - 1);
    int y = (idx >> 7) & (H - 1);
    int o = (idx >> 14) & 1;
    int b = idx >> 15;

    const float* fb = flows + (size_t)b * 2 * FH * FW;
    const float* cw = conv_w + o * 2 * 16;

    float acc = 0.f;
#pragma unroll
    for (int i = 0; i < 2; ++i) {
        const float* fi = fb + (size_t)i * FH * FW;
#pragma unroll
        for (int kh = 0; kh < 4; ++kh) {
            const float4 v = *reinterpret_cast<const float4*>(
                fi + (size_t)(4 * y + kh) * FW + 4 * x);
            const float* w = cw + i * 16 + kh * 4;
            acc += v.x * w[0] + v.y * w[1] + v.z * w[2] + v.w * w[3];
        }
    }
    f[idx] = acc;
}

// ---------------------------------------------------------------------------
// Kernel 2: bilinear warp via LDS row staging.
// Block = (b, 16-row tile, 8 channels). Per channel: stage 23 rows (halo +-3/+4)
// into LDS with coalesced float4 loads (prefetched one channel ahead into
// registers), then interpolate from LDS with per-thread register weights.
// Fallback: pixels whose (clamped) source rows fall outside the staged halo
// re-gather from global (correct for arbitrary flow; never taken for this data).
// ---------------------------------------------------------------------------
__global__ __launch_bounds__(256, 4) void warp_kernel(
    const float* __restrict__ feat,
    const float* __restrict__ f,
    float* __restrict__ out)
{
    __shared__ float smem[SR * W];   // 11776 B

    const int bid = blockIdx.x;
    const int cg  = bid & (CGN - 1);
    const int rg  = (bid >> 5) & (RG - 1);
    const int b   = bid >> 8;
    const int tid = threadIdx.x;
    const int ybase = rg * TR;
    const int row0  = ybase - 3;          // source row of LDS slot 0 (unclamped)
    const int pixbase = ybase * W;

    const size_t cslice = (size_t)HW;
    const float* featb = feat + ((size_t)b * C + (size_t)cg * CG) * cslice;
    float*       outb  = out  + ((size_t)b * C + (size_t)cg * CG) * cslice;

    // ---- prefetch channel 0 stage into registers (hides under weight math)
    float4 streg[3];
#pragma unroll
    for (int j = 0; j < 3; ++j) {
        const int t2 = tid + j * 256;
        if (t2 < CHUNKS) {
            const int r = t2 >> 5;                       // staged row slot
            const int grow = min(max(row0 + r, 0), H - 1);
            streg[j] = *reinterpret_cast<const float4*>(
                featb + (size_t)grow * W + (t2 & 31) * 4);
        }
    }

    // ---- phase 0: per-thread weights for its 8 pixels (registers)
    int   i0b[PXT], i1b[PXT];
    float a0[PXT], b0[PXT], a1[PXT], b1[PXT];
    int okmask = 0;
#pragma unroll
    for (int u = 0; u < PXT; ++u) {
        const int pl = u * 256 + tid;          // 0..2047 within tile
        const int px = pixbase + pl;
        const int x = px & (W - 1);
        const int y = px >> 7;
        const float fx = f[(size_t)(b * 2 + 0) * HW + px];
        const float fy = f[(size_t)(b * 2 + 1) * HW + px];
        const float gx = (float)x + fx;
        const float gy = (float)y + fy;
        const float x0f = floorf(gx);
        const float y0f = floorf(gy);
        const float wx = gx - x0f;
        const float wy = gy - y0f;
        const int x0 = (int)x0f, y0 = (int)y0f;
        const int y1 = y0 + 1;

        const float u0 = 1.f - wx, u1 = wx;
        float A, Bv;
        if (x0 >= 0 && x0 <= W - 2)      { A = u0;  Bv = u1;  }
        else if (x0 == W - 1)            { A = 0.f; Bv = u0;  }
        else if (x0 == -1)               { A = u1;  Bv = 0.f; }
        else                             { A = 0.f; Bv = 0.f; }
        const int bx = min(max(x0, 0), W - 2);

        const float vy0 = (y0 >= 0 && y0 < H) ? 1.f : 0.f;
        const float vy1 = (y1 >= 0 && y1 < H) ? 1.f : 0.f;
        const int cy0 = min(max(y0, 0), H - 1);
        const int cy1 = min(max(y1, 0), H - 1);

        const int s0 = cy0 - row0;
        const int s1 = cy1 - row0;
        const bool ok = (s0 >= 0) && (s1 < SR);
        okmask |= ok ? (1 << u) : 0;
        const int cs0 = min(max(s0, 0), SR - 1);
        const int cs1 = min(max(s1, 0), SR - 1);
        i0b[u] = cs0 * W + bx;
        i1b[u] = cs1 * W + bx;

        const float wy0 = (1.f - wy) * vy0;
        const float wy1 = wy * vy1;
        a0[u] = A * wy0;  b0[u] = Bv * wy0;
        a1[u] = A * wy1;  b1[u] = Bv * wy1;
    }

    // ---- channel loop: write staged regs -> LDS, prefetch next, compute
    for (int cc = 0; cc < CG; ++cc) {
        __syncthreads();   // prior channel's readers done with smem
#pragma unroll
        for (int j = 0; j < 3; ++j) {
            const int t2 = tid + j * 256;
            if (t2 < CHUNKS)
                *reinterpret_cast<float4*>(&smem[t2 * 4]) = streg[j];
        }
        __syncthreads();   // staged rows visible to all waves

        // prefetch next channel (last iter re-reads current; harmless)
        const int cn = min(cc + 1, CG - 1);
        float4 nreg[3];
#pragma unroll
        for (int j = 0; j < 3; ++j) {
            const int t2 = tid + j * 256;
            if (t2 < CHUNKS) {
                const int r = t2 >> 5;
                const int grow = min(max(row0 + r, 0), H - 1);
                nreg[j] = *reinterpret_cast<const float4*>(
                    featb + (size_t)cn * cslice + (size_t)grow * W + (t2 & 31) * 4);
            }
        }

        // compute + store
        float* qc = outb + (size_t)cc * cslice + pixbase;
#pragma unroll
        for (int u = 0; u < PXT; ++u) {
            const int pl = u * 256 + tid;
            const float r00 = smem[i0b[u]], r01 = smem[i0b[u] + 1];
            const float r10 = smem[i1b[u]], r11 = smem[i1b[u] + 1];
            float v = r00 * a0[u] + r01 * b0[u] + r10 * a1[u] + r11 * b1[u];
            if (__builtin_expect((okmask >> u & 1) == 0, 0)) {
                // Rare fallback: flow exceeded halo. Recompute indices, gather
                // from global with the (already validity-masked) weights.
                const int px = pixbase + pl;
                const int x = px & (W - 1);
                const int y = px >> 7;
                const float fx = f[(size_t)(b * 2 + 0) * HW + px];
                const float fy = f[(size_t)(b * 2 + 1) * HW + px];
                const int x0 = (int)floorf((float)x + fx);
                const int y0 = (int)floorf((float)y + fy);
                const int bx  = min(max(x0, 0), W - 2);
                const int cy0 = min(max(y0, 0), H - 1);
                const int cy1 = min(max(y0 + 1, 0), H - 1);
                const float* fc = featb + (size_t)cc * cslice;
                v = fc[cy0 * W + bx]     * a0[u] + fc[cy0 * W + bx + 1] * b0[u]
                  + fc[cy1 * W + bx]     * a1[u] + fc[cy1 * W + bx + 1] * b1[u];
            }
            qc[pl] = v;
        }

#pragma unroll
        for (int j = 0; j < 3; ++j) streg[j] = nreg[j];
    }
}

// ---------------------------------------------------------------------------
extern "C" void kernel_launch(void* const* d_in, const int* in_sizes, int n_in,
                              void* d_out, int out_size, void* d_ws, size_t ws_size,
                              hipStream_t stream)
{
    const float* features = (const float*)d_in[0];
    const float* flows    = (const float*)d_in[1];
    const float* conv_w   = (const float*)d_in[2];
    float*       out      = (float*)d_out;
    float*       f        = (float*)d_ws;   // [B,2,H,W] = 1 MiB

    downsample_kernel<<<1024, 256, 0, stream>>>(flows, conv_w, f);
    // B * RG * CGN = 8 * 8 * 32 = 2048 blocks
    warp_kernel<<<B * RG * CGN, 256, 0, stream>>>(features, f, out);
}

// Round 8
// 96.566 us; speedup vs baseline: 2.1679x; 2.1679x over previous
//
#include <hip/hip_runtime.h>

// Problem constants (fixed by setup_inputs)
#define B   8
#define C   256
#define H   128
#define W   128
#define HW  (H * W)
#define FH  512
#define FW  512

typedef float f32x2 __attribute__((ext_vector_type(2)));

// ---------------------------------------------------------------------------
// Kernel 1: strided 4x4 conv downsample of flows using runtime conv_w.
// ---------------------------------------------------------------------------
__global__ __launch_bounds__(256) void downsample_kernel(
    const float* __restrict__ flows,
    const float* __restrict__ conv_w,
    float* __restrict__ f)
{
    int idx = blockIdx.x * blockDim.x + threadIdx.x;
    if (idx >= B * 2 * H * W) return;
    int x = idx & (W - 1);
    int y = (idx >> 7) & (H - 1);
    int o = (idx >> 14) & 1;
    int b = idx >> 15;

    const float* fb = flows + (size_t)b * 2 * FH * FW;
    const float* cw = conv_w + o * 2 * 16;

    float acc = 0.f;
#pragma unroll
    for (int i = 0; i < 2; ++i) {
        const float* fi = fb + (size_t)i * FH * FW;
#pragma unroll
        for (int kh = 0; kh < 4; ++kh) {
            const float4 v = *reinterpret_cast<const float4*>(
                fi + (size_t)(4 * y + kh) * FW + 4 * x);
            const float* w = cw + i * 16 + kh * 4;
            acc += v.x * w[0] + v.y * w[1] + v.z * w[2] + v.w * w[3];
        }
    }
    f[idx] = acc;
}

// ---------------------------------------------------------------------------
// Kernel 2: bilinear warp, pair-load, asm-controlled VMEM pipeline.
// Store-exempt counted vmcnt: body order [WAIT(N), FMA, PREFETCH(c+4),
// STORE(c)] guarantees each wait covers only loads; stores get >=4
// iterations of slack and are never drained inside the loop.
// ---------------------------------------------------------------------------
#define PPB 64   // pixels per block

__global__ __launch_bounds__(256, 4) void warp_kernel(
    const float* __restrict__ feat,
    const float* __restrict__ f,
    float* __restrict__ out)
{
    __shared__ int   s_i0[PPB], s_i1[PPB];
    __shared__ float s_a0[PPB], s_b0[PPB], s_a1[PPB], s_b1[PPB];

    // XCD-aware swizzle (2048 blocks, 8 XCDs): each XCD owns one batch image.
    const int hw_bid = blockIdx.x;
    const int bid = (hw_bid & 7) * 256 + (hw_bid >> 3);

    const int tid = threadIdx.x;
    const int blocks_per_img = HW / PPB;               // 256
    const int b = bid / blocks_per_img;
    const int pix_base = (bid % blocks_per_img) * PPB;

    if (tid < PPB) {
        const int p = pix_base + tid;
        const int x = p & (W - 1);
        const int y = p >> 7;
        const float fx = f[(size_t)(b * 2 + 0) * HW + p];
        const float fy = f[(size_t)(b * 2 + 1) * HW + p];
        const float gx = (float)x + fx;
        const float gy = (float)y + fy;
        const float x0f = floorf(gx);
        const float y0f = floorf(gy);
        const float wx = gx - x0f;
        const float wy = gy - y0f;
        const int x0 = (int)x0f, y0 = (int)y0f;
        const int y1 = y0 + 1;

        const float u0 = 1.f - wx, u1 = wx;
        float A, Bv;
        if (x0 >= 0 && x0 <= W - 2)      { A = u0;  Bv = u1;  }
        else if (x0 == W - 1)            { A = 0.f; Bv = u0;  }
        else if (x0 == -1)               { A = u1;  Bv = 0.f; }
        else                             { A = 0.f; Bv = 0.f; }
        const int bx = min(max(x0, 0), W - 2);

        const float vy0 = (y0 >= 0 && y0 < H) ? 1.f : 0.f;
        const float vy1 = (y1 >= 0 && y1 < H) ? 1.f : 0.f;
        const int cy0 = min(max(y0, 0), H - 1);
        const int cy1 = min(max(y1, 0), H - 1);

        s_i0[tid] = cy0 * W + bx;
        s_i1[tid] = cy1 * W + bx;
        const float wy0 = (1.f - wy) * vy0;
        const float wy1 = wy * vy1;
        s_a0[tid] = A * wy0;  s_b0[tid] = Bv * wy0;
        s_a1[tid] = A * wy1;  s_b1[tid] = Bv * wy1;
    }
    __syncthreads();

    const int pl   = tid & (PPB - 1);   // pixel lane
    const int cofs = tid >> 6;          // wave id -> channel offset 0..3

    const int   i0 = s_i0[pl], i1 = s_i1[pl];
    const float a0 = s_a0[pl], b0 = s_b0[pl];
    const float a1 = s_a1[pl], b1 = s_b1[pl];

    const float* fb = feat + (size_t)b * C * HW;
    float*       ob = out  + (size_t)b * C * HW + pix_base;

    const float* pbase = fb + (size_t)cofs * HW;
    float*       q     = ob + (size_t)cofs * HW + pl;

    // 4 load double-buffers (rotating), each = {row0 pair, row1 pair}
    f32x2 r0a, r0b, r1a, r1b, r2a, r2b, r3a, r3b;

#define ISSUE(ra, rb, cidx) do {                                              \
        const float* _pc = pbase + (size_t)(cidx) * (4 * HW);                 \
        asm volatile("global_load_dwordx2 %0, %1, off"                        \
                     : "=v"(ra) : "v"(_pc + i0));                             \
        asm volatile("global_load_dwordx2 %0, %1, off"                        \
                     : "=v"(rb) : "v"(_pc + i1));                             \
    } while (0)

    // body: WAIT(vm) -> FMA -> [PREFETCH cpre] -> STORE c
#define BODY_PF(ra, rb, c, cpre, vm) do {                                     \
        asm volatile("s_waitcnt vmcnt(" #vm ")" ::: "memory");                \
        __builtin_amdgcn_sched_barrier(0);                                    \
        float _v = ra.x * a0 + ra.y * b0 + rb.x * a1 + rb.y * b1;             \
        ISSUE(ra, rb, (cpre));                                                \
        float* _q = q + (size_t)(c) * (4 * HW);                               \
        asm volatile("global_store_dword %0, %1, off"                         \
                     :: "v"(_q), "v"(_v) : "memory");                         \
    } while (0)

#define BODY_NP(ra, rb, c, vm) do {                                           \
        asm volatile("s_waitcnt vmcnt(" #vm ")" ::: "memory");                \
        __builtin_amdgcn_sched_barrier(0);                                    \
        float _v = ra.x * a0 + ra.y * b0 + rb.x * a1 + rb.y * b1;             \
        float* _q = q + (size_t)(c) * (4 * HW);                               \
        asm volatile("global_store_dword %0, %1, off"                         \
                     :: "v"(_q), "v"(_v) : "memory");                         \
    } while (0)

    // prologue: channels 0..3 in flight
    ISSUE(r0a, r0b, 0);
    ISSUE(r1a, r1b, 1);
    ISSUE(r2a, r2b, 2);
    ISSUE(r3a, r3b, 3);

    // head (exact issue-order counts: loads-only ahead, stores accumulate)
    BODY_PF(r0a, r0b, 0, 4, 6);
    BODY_PF(r1a, r1b, 1, 5, 7);
    BODY_PF(r2a, r2b, 2, 6, 8);
    BODY_PF(r3a, r3b, 3, 7, 9);

    // steady state: 4 stores + 6 loads younger than the waited pair -> vmcnt(10)
    for (int c4 = 4; c4 <= 56; c4 += 4) {
        BODY_PF(r0a, r0b, c4 + 0, c4 + 4, 10);
        BODY_PF(r1a, r1b, c4 + 1, c4 + 5, 10);
        BODY_PF(r2a, r2b, c4 + 2, c4 + 6, 10);
        BODY_PF(r3a, r3b, c4 + 3, c4 + 7, 10);
    }

    // tail: channels 60..63, no prefetch; counts shrink as pipeline drains
    BODY_NP(r0a, r0b, 60, 10);
    BODY_NP(r1a, r1b, 61, 8);
    BODY_NP(r2a, r2b, 62, 6);
    BODY_NP(r3a, r3b, 63, 4);

#undef ISSUE
#undef BODY_PF
#undef BODY_NP
}

// ---------------------------------------------------------------------------
extern "C" void kernel_launch(void* const* d_in, const int* in_sizes, int n_in,
                              void* d_out, int out_size, void* d_ws, size_t ws_size,
                              hipStream_t stream)
{
    const float* features = (const float*)d_in[0];
    const float* flows    = (const float*)d_in[1];
    const float* conv_w   = (const float*)d_in[2];
    float*       out      = (float*)d_out;
    float*       f        = (float*)d_ws;   // [B,2,H,W] = 1 MiB

    downsample_kernel<<<1024, 256, 0, stream>>>(flows, conv_w, f);
    warp_kernel<<<2048, 256, 0, stream>>>(features, f, out);
}

// Round 9
// 71.347 us; speedup vs baseline: 2.9342x; 1.3535x over previous
//
#include <hip/hip_runtime.h>

// Problem constants (fixed by setup_inputs)
#define B   8
#define C   256
#define H   128
#define W   128
#define HW  (H * W)
#define FH  512
#define FW  512

// Tiling
#define TR     16              // output rows per tile
#define SLOTS  24              // staged row slots (rows row0..row0+23, clamped)
#define HALO   3               // rows staged above tile: row0 = ybase-3
#define CG     8               // channels per block
#define RGN    (H / TR)        // 8 row-groups
#define CGN    (C / CG)        // 32 channel-groups
#define PXB    (TR * W)        // 2048 pixels per tile
#define PXT    (PXB / 256)     // 8 pixels per thread
#define CHUNKS (SLOTS * W / 4) // 768 float4 chunks per row buffer (3/thread)

typedef float f32x4v __attribute__((ext_vector_type(4)));

// ---------------------------------------------------------------------------
// Kernel 1: strided 4x4 conv downsample of flows using runtime conv_w.
// ---------------------------------------------------------------------------
__global__ __launch_bounds__(256) void downsample_kernel(
    const float* __restrict__ flows,
    const float* __restrict__ conv_w,
    float* __restrict__ f)
{
    int idx = blockIdx.x * blockDim.x + threadIdx.x;
    if (idx >= B * 2 * H * W) return;
    int x = idx & (W - 1);
    int y = (idx >> 7) & (H - 1);
    int o = (idx >> 14) & 1;
    int b = idx >> 15;

    const float* fb = flows + (size_t)b * 2 * FH * FW;
    const float* cw = conv_w + o * 2 * 16;

    float acc = 0.f;
#pragma unroll
    for (int i = 0; i < 2; ++i) {
        const float* fi = fb + (size_t)i * FH * FW;
#pragma unroll
        for (int kh = 0; kh < 4; ++kh) {
            const float4 v = *reinterpret_cast<const float4*>(
                fi + (size_t)(4 * y + kh) * FW + 4 * x);
            const float* w = cw + i * 16 + kh * 4;
            acc += v.x * w[0] + v.y * w[1] + v.z * w[2] + v.w * w[3];
        }
    }
    f[idx] = acc;
}

// ---------------------------------------------------------------------------
// Kernel 2: bilinear warp, zero global gathers.
// Block = (b, 16-row tile, 8 channels). Weights/indices -> LDS once.
// Feature rows staged per channel into double-buffered LDS via asm-pinned
// coalesced dwordx4 prefetch (issued before compute, ds-written after a
// counted vmcnt(8) — the 8 compute stores make the count safe).
// One barrier per channel. Interpolation reads are LDS-only.
// ---------------------------------------------------------------------------
__global__ __launch_bounds__(256, 2) void warp_kernel(
    const float* __restrict__ feat,
    const float* __restrict__ f,
    float* __restrict__ out)
{
    __shared__ __align__(16) float rows[2][SLOTS * W];  // 2 x 12 KB
    __shared__ int2   iL[PXB];                          // 16 KB
    __shared__ float4 wL[PXB];                          // 32 KB

    // XCD-chunked swizzle; rg fastest so same-XCD blocks share halo rows.
    const int hw_bid = blockIdx.x;
    const int lin = (hw_bid & 7) * 256 + (hw_bid >> 3);
    const int rg = lin & (RGN - 1);
    const int cg = (lin >> 3) & (CGN - 1);
    const int b  = lin >> 8;

    const int tid = threadIdx.x;
    const int ybase = rg * TR;
    const int row0  = ybase - HALO;
    const int pixbase = ybase * W;

    const float* featb = feat + ((size_t)b * C + (size_t)cg * CG) * HW;
    float*       outc  = out  + ((size_t)b * C + (size_t)cg * CG) * HW + pixbase;
    const float* fx_p  = f + (size_t)(b * 2 + 0) * HW;
    const float* fy_p  = f + (size_t)(b * 2 + 1) * HW;

    // Channel-invariant staging offsets (float units) for this thread's 3 chunks.
    int goff[3];
#pragma unroll
    for (int j = 0; j < 3; ++j) {
        const int chunk = j * 256 + tid;
        const int grow = min(max(row0 + (chunk >> 5), 0), H - 1);
        goff[j] = grow * W + (chunk & 31) * 4;
    }

    f32x4v nx0, nx1, nx2;
#define PREF(ch) do {                                                         \
        const float* _cb = featb + (size_t)(ch) * HW;                         \
        asm volatile("global_load_dwordx4 %0, %1, off"                        \
                     : "=v"(nx0) : "v"(_cb + goff[0]) : "memory");            \
        asm volatile("global_load_dwordx4 %0, %1, off"                        \
                     : "=v"(nx1) : "v"(_cb + goff[1]) : "memory");            \
        asm volatile("global_load_dwordx4 %0, %1, off"                        \
                     : "=v"(nx2) : "v"(_cb + goff[2]) : "memory");            \
    } while (0)

#define STASH(buf) do {                                                       \
        *reinterpret_cast<f32x4v*>(&rows[(buf)][(0 * 256 + tid) * 4]) = nx0;  \
        *reinterpret_cast<f32x4v*>(&rows[(buf)][(1 * 256 + tid) * 4]) = nx1;  \
        *reinterpret_cast<f32x4v*>(&rows[(buf)][(2 * 256 + tid) * 4]) = nx2;  \
    } while (0)

    // ---- prologue: channel-0 stage in flight, weights -> LDS meanwhile
    PREF(0);

#pragma unroll 2
    for (int k = 0; k < PXT; ++k) {
        const int px = tid + (k << 8);
        const int gpx = pixbase + px;
        const int x = gpx & (W - 1);
        const int y = gpx >> 7;
        const float gx = (float)x + fx_p[gpx];
        const float gy = (float)y + fy_p[gpx];
        const float x0f = floorf(gx);
        const float y0f = floorf(gy);
        const float wx = gx - x0f;
        const float wy = gy - y0f;
        const int x0 = (int)x0f, y0 = (int)y0f;
        const int y1 = y0 + 1;

        const float u0 = 1.f - wx, u1 = wx;
        float A, Bv;
        if (x0 >= 0 && x0 <= W - 2)      { A = u0;  Bv = u1;  }
        else if (x0 == W - 1)            { A = 0.f; Bv = u0;  }
        else if (x0 == -1)               { A = u1;  Bv = 0.f; }
        else                             { A = 0.f; Bv = 0.f; }
        const int bx = min(max(x0, 0), W - 2);

        const float vy0 = (y0 >= 0 && y0 < H) ? 1.f : 0.f;
        const float vy1 = (y1 >= 0 && y1 < H) ? 1.f : 0.f;
        const int cy0 = min(max(y0, 0), H - 1);
        const int cy1 = min(max(y1, 0), H - 1);

        const int s0 = cy0 - row0;
        const int s1 = cy1 - row0;
        const bool ok = (s0 >= 0) && (s1 < SLOTS);
        const int cs0 = min(max(s0, 0), SLOTS - 1);
        const int cs1 = min(max(s1, 0), SLOTS - 1);
        int i0 = cs0 * W + bx;
        const int i1 = cs1 * W + bx;
        if (!ok) i0 |= (1 << 30);

        const float wy0 = (1.f - wy) * vy0;
        const float wy1 = wy * vy1;
        iL[px] = make_int2(i0, i1);
        wL[px] = make_float4(A * wy0, Bv * wy0, A * wy1, Bv * wy1);
    }

    asm volatile("s_waitcnt vmcnt(0)" ::: "memory");
    __builtin_amdgcn_sched_barrier(0);
    STASH(0);
    __syncthreads();

    // ---- channel loop: prefetch(ch+1) || compute(ch) ; stash ; barrier
    for (int ch = 0; ch < CG; ++ch) {
        if (ch < CG - 1) PREF(ch + 1);

        const float* rb = &rows[ch & 1][0];
        float* oc = outc + (size_t)ch * HW;
#pragma unroll
        for (int k = 0; k < PXT; ++k) {
            const int px = tid + (k << 8);
            const int2   ii = iL[px];
            const float4 w  = wL[px];
            float v;
            if (__builtin_expect((ii.x >> 30) & 1, 0)) {
                // Flow exceeded staged halo: correct global fallback.
                const int gpx = pixbase + px;
                const int x = gpx & (W - 1);
                const int y = gpx >> 7;
                const int x0 = (int)floorf((float)x + fx_p[gpx]);
                const int y0 = (int)floorf((float)y + fy_p[gpx]);
                const int bx  = min(max(x0, 0), W - 2);
                const int cy0 = min(max(y0, 0), H - 1);
                const int cy1 = min(max(y0 + 1, 0), H - 1);
                const float* fc = featb + (size_t)ch * HW;
                v = fc[cy0 * W + bx]     * w.x + fc[cy0 * W + bx + 1] * w.y
                  + fc[cy1 * W + bx]     * w.z + fc[cy1 * W + bx + 1] * w.w;
            } else {
                v = rb[ii.x] * w.x + rb[ii.x + 1] * w.y
                  + rb[ii.y] * w.z + rb[ii.y + 1] * w.w;
            }
            oc[px] = v;
        }

        if (ch < CG - 1) {
            // 8 stores above are newer than PREF(ch+1) -> vmcnt(8) is safe
            // (over-waiting only if fallback loads were issued).
            asm volatile("s_waitcnt vmcnt(8)" ::: "memory");
            __builtin_amdgcn_sched_barrier(0);
            STASH((ch + 1) & 1);
        }
        __syncthreads();
    }
#undef PREF
#undef STASH
}

// ---------------------------------------------------------------------------
extern "C" void kernel_launch(void* const* d_in, const int* in_sizes, int n_in,
                              void* d_out, int out_size, void* d_ws, size_t ws_size,
                              hipStream_t stream)
{
    const float* features = (const float*)d_in[0];
    const float* flows    = (const float*)d_in[1];
    const float* conv_w   = (const float*)d_in[2];
    float*       out      = (float*)d_out;
    float*       f        = (float*)d_ws;   // [B,2,H,W] = 1 MiB

    downsample_kernel<<<1024, 256, 0, stream>>>(flows, conv_w, f);
    // B * RGN * CGN = 8 * 8 * 32 = 2048 blocks
    warp_kernel<<<2048, 256, 0, stream>>>(features, f, out);
}

// Round 10
// 66.029 us; speedup vs baseline: 3.1706x; 1.0805x over previous
//
#include <hip/hip_runtime.h>

// Problem constants (fixed by setup_inputs)
#define B   8
#define C   256
#define H   128
#define W   128
#define HW  (H * W)
#define FH  512
#define FW  512

// Tiling
#define TR     16              // output rows per tile
#define SLOTS  24              // staged row slots (rows row0..row0+23, clamped)
#define HALO   3               // rows staged above tile: row0 = ybase-3
#define CG     8               // channels per block
#define RGN    (H / TR)        // 8 row-groups
#define CGN    (C / CG)        // 32 channel-groups
#define PXB    (TR * W)        // 2048 pixels per tile
#define CHUNKS (SLOTS * W / 4) // 768 float4 chunks = 3 per thread exactly

typedef float f32x4v __attribute__((ext_vector_type(4)));

// ---------------------------------------------------------------------------
// Kernel 1: strided 4x4 conv downsample of flows using runtime conv_w.
// ---------------------------------------------------------------------------
__global__ __launch_bounds__(256) void downsample_kernel(
    const float* __restrict__ flows,
    const float* __restrict__ conv_w,
    float* __restrict__ f)
{
    int idx = blockIdx.x * blockDim.x + threadIdx.x;
    if (idx >= B * 2 * H * W) return;
    int x = idx & (W - 1);
    int y = (idx >> 7) & (H - 1);
    int o = (idx >> 14) & 1;
    int b = idx >> 15;

    const float* fb = flows + (size_t)b * 2 * FH * FW;
    const float* cw = conv_w + o * 2 * 16;

    float acc = 0.f;
#pragma unroll
    for (int i = 0; i < 2; ++i) {
        const float* fi = fb + (size_t)i * FH * FW;
#pragma unroll
        for (int kh = 0; kh < 4; ++kh) {
            const float4 v = *reinterpret_cast<const float4*>(
                fi + (size_t)(4 * y + kh) * FW + 4 * x);
            const float* w = cw + i * 16 + kh * 4;
            acc += v.x * w[0] + v.y * w[1] + v.z * w[2] + v.w * w[3];
        }
    }
    f[idx] = acc;
}

// ---------------------------------------------------------------------------
// Kernel 2: bilinear warp, zero global gathers, register-resident weights.
// Block = (b, 16-row tile, 8 channels). Per-pixel idx/weights live in NAMED
// per-thread registers (no arrays -> no scratch). LDS = 2x12KB row buffers
// only -> >=3 blocks/CU. Rows staged per channel via asm-pinned coalesced
// dwordx4 prefetch; counted vmcnt(8) (8 compute stores newer than the 3
// prefetch loads); one barrier per channel.
// ---------------------------------------------------------------------------
__global__ __launch_bounds__(256, 3) void warp_kernel(
    const float* __restrict__ feat,
    const float* __restrict__ f,
    float* __restrict__ out)
{
    __shared__ __align__(16) float rows[2][SLOTS * W];  // 24 KB total

    // XCD-chunked swizzle; rg fastest so same-XCD blocks share halo rows.
    const int hw_bid = blockIdx.x;
    const int lin = (hw_bid & 7) * 256 + (hw_bid >> 3);
    const int rg = lin & (RGN - 1);
    const int cg = (lin >> 3) & (CGN - 1);
    const int b  = lin >> 8;

    const int tid = threadIdx.x;
    const int ybase = rg * TR;
    const int row0  = ybase - HALO;
    const int pixbase = ybase * W;

    const float* featb = feat + ((size_t)b * C + (size_t)cg * CG) * HW;
    float*       outc  = out  + ((size_t)b * C + (size_t)cg * CG) * HW + pixbase;
    const float* fx_p  = f + (size_t)(b * 2 + 0) * HW;
    const float* fy_p  = f + (size_t)(b * 2 + 1) * HW;

    // Channel-invariant staging offsets (float units) for this thread's 3 chunks.
    int goff0, goff1, goff2;
    {
        const int c0 = tid,          r0c = min(max(row0 + (c0 >> 5), 0), H - 1);
        const int c1 = 256 + tid,    r1c = min(max(row0 + (c1 >> 5), 0), H - 1);
        const int c2 = 512 + tid,    r2c = min(max(row0 + (c2 >> 5), 0), H - 1);
        goff0 = r0c * W + (c0 & 31) * 4;
        goff1 = r1c * W + (c1 & 31) * 4;
        goff2 = r2c * W + (c2 & 31) * 4;
    }

    f32x4v nx0, nx1, nx2;
#define PREF(ch) do {                                                         \
        const float* _cb = featb + (size_t)(ch) * HW;                         \
        asm volatile("global_load_dwordx4 %0, %1, off"                        \
                     : "=v"(nx0) : "v"(_cb + goff0) : "memory");              \
        asm volatile("global_load_dwordx4 %0, %1, off"                        \
                     : "=v"(nx1) : "v"(_cb + goff1) : "memory");              \
        asm volatile("global_load_dwordx4 %0, %1, off"                        \
                     : "=v"(nx2) : "v"(_cb + goff2) : "memory");              \
    } while (0)

#define STASH(buf) do {                                                       \
        *reinterpret_cast<f32x4v*>(&rows[(buf)][(0 * 256 + tid) * 4]) = nx0;  \
        *reinterpret_cast<f32x4v*>(&rows[(buf)][(1 * 256 + tid) * 4]) = nx1;  \
        *reinterpret_cast<f32x4v*>(&rows[(buf)][(2 * 256 + tid) * 4]) = nx2;  \
    } while (0)

    // ---- prologue: channel-0 stage in flight; weights -> registers meanwhile
    PREF(0);

    // Named per-pixel state (NO arrays -> guaranteed registers, R7 lesson).
#define PXDECL(k) int i0_##k, i1_##k; float w0_##k, w1_##k, w2_##k, w3_##k;
    PXDECL(0) PXDECL(1) PXDECL(2) PXDECL(3)
    PXDECL(4) PXDECL(5) PXDECL(6) PXDECL(7)

#define WCOMP(k) do {                                                         \
        const int px  = tid + ((k) << 8);                                     \
        const int gpx = pixbase + px;                                         \
        const int x = gpx & (W - 1);                                          \
        const int y = gpx >> 7;                                               \
        const float gx = (float)x + fx_p[gpx];                                \
        const float gy = (float)y + fy_p[gpx];                                \
        const float x0f = floorf(gx);                                         \
        const float y0f = floorf(gy);                                         \
        const float wx = gx - x0f;                                            \
        const float wy = gy - y0f;                                            \
        const int x0 = (int)x0f, y0 = (int)y0f;                               \
        const int y1 = y0 + 1;                                                \
        const float u0 = 1.f - wx, u1 = wx;                                   \
        float A, Bv;                                                          \
        if (x0 >= 0 && x0 <= W - 2)      { A = u0;  Bv = u1;  }               \
        else if (x0 == W - 1)            { A = 0.f; Bv = u0;  }               \
        else if (x0 == -1)               { A = u1;  Bv = 0.f; }               \
        else                             { A = 0.f; Bv = 0.f; }               \
        const int bx = min(max(x0, 0), W - 2);                                \
        const float vy0 = (y0 >= 0 && y0 < H) ? 1.f : 0.f;                    \
        const float vy1 = (y1 >= 0 && y1 < H) ? 1.f : 0.f;                    \
        const int cy0 = min(max(y0, 0), H - 1);                               \
        const int cy1 = min(max(y1, 0), H - 1);                               \
        const int s0 = cy0 - row0;                                            \
        const int s1 = cy1 - row0;                                            \
        const bool ok = (s0 >= 0) && (s1 < SLOTS);                            \
        const int cs0 = min(max(s0, 0), SLOTS - 1);                           \
        const int cs1 = min(max(s1, 0), SLOTS - 1);                           \
        i0_##k = (cs0 * W + bx) | (ok ? 0 : (int)0x80000000);                 \
        i1_##k = cs1 * W + bx;                                                \
        const float wy0 = (1.f - wy) * vy0;                                   \
        const float wy1 = wy * vy1;                                           \
        w0_##k = A * wy0;  w1_##k = Bv * wy0;                                 \
        w2_##k = A * wy1;  w3_##k = Bv * wy1;                                 \
    } while (0)

    WCOMP(0); WCOMP(1); WCOMP(2); WCOMP(3);
    WCOMP(4); WCOMP(5); WCOMP(6); WCOMP(7);

    asm volatile("s_waitcnt vmcnt(0)" ::: "memory");
    __builtin_amdgcn_sched_barrier(0);
    STASH(0);
    __syncthreads();

    // Per-pixel compute: LDS gather with register weights; rare global fallback.
#define CPX(k, rb, oc, ch) do {                                               \
        const int px = tid + ((k) << 8);                                      \
        float v;                                                              \
        if (__builtin_expect(i0_##k < 0, 0)) {                                \
            const int gpx = pixbase + px;                                     \
            const int x = gpx & (W - 1);                                      \
            const int y = gpx >> 7;                                           \
            const int x0 = (int)floorf((float)x + fx_p[gpx]);                 \
            const int y0 = (int)floorf((float)y + fy_p[gpx]);                 \
            const int bx  = min(max(x0, 0), W - 2);                           \
            const int cy0 = min(max(y0, 0), H - 1);                           \
            const int cy1 = min(max(y0 + 1, 0), H - 1);                       \
            const float* fc = featb + (size_t)(ch) * HW;                      \
            v = fc[cy0 * W + bx]     * w0_##k + fc[cy0 * W + bx + 1] * w1_##k \
              + fc[cy1 * W + bx]     * w2_##k + fc[cy1 * W + bx + 1] * w3_##k;\
        } else {                                                              \
            v = rb[i0_##k] * w0_##k + rb[i0_##k + 1] * w1_##k                 \
              + rb[i1_##k] * w2_##k + rb[i1_##k + 1] * w3_##k;                \
        }                                                                     \
        oc[px] = v;                                                           \
    } while (0)

    // ---- channel loop: prefetch(ch+1) || compute(ch) ; stash ; barrier
    for (int ch = 0; ch < CG; ++ch) {
        if (ch < CG - 1) PREF(ch + 1);

        const float* rb = &rows[ch & 1][0];
        float* oc = outc + (size_t)ch * HW;
        CPX(0, rb, oc, ch); CPX(1, rb, oc, ch);
        CPX(2, rb, oc, ch); CPX(3, rb, oc, ch);
        CPX(4, rb, oc, ch); CPX(5, rb, oc, ch);
        CPX(6, rb, oc, ch); CPX(7, rb, oc, ch);

        if (ch < CG - 1) {
            // The 8 compute stores are newer than PREF's 3 loads -> vmcnt(8)
            // waits exactly for the prefetch (fallback loads only add slack).
            asm volatile("s_waitcnt vmcnt(8)" ::: "memory");
            __builtin_amdgcn_sched_barrier(0);
            STASH((ch + 1) & 1);
            __syncthreads();
        }
    }
#undef PREF
#undef STASH
#undef PXDECL
#undef WCOMP
#undef CPX
}

// ---------------------------------------------------------------------------
extern "C" void kernel_launch(void* const* d_in, const int* in_sizes, int n_in,
                              void* d_out, int out_size, void* d_ws, size_t ws_size,
                              hipStream_t stream)
{
    const float* features = (const float*)d_in[0];
    const float* flows    = (const float*)d_in[1];
    const float* conv_w   = (const float*)d_in[2];
    float*       out      = (float*)d_out;
    float*       f        = (float*)d_ws;   // [B,2,H,W] = 1 MiB

    downsample_kernel<<<1024, 256, 0, stream>>>(flows, conv_w, f);
    // B * RGN * CGN = 8 * 8 * 32 = 2048 blocks
    warp_kernel<<<2048, 256, 0, stream>>>(features, f, out);
}